// Round 7
// baseline (162.204 us; speedup 1.0000x reference)
//
#include <hip/hip_runtime.h>

#define NV    10
#define DD    2048
#define TAPS  25
#define CHUNK 128               // channels per staged chunk
#define NCH   (DD / CHUNK)      // 16 chunks
#define CF4   ((CHUNK * TAPS) / 4)  // 800 float4 per chunk
#define OB    64

typedef __attribute__((address_space(1))) const unsigned int gu32;
typedef __attribute__((address_space(3))) unsigned int lu32;

__device__ __forceinline__ float bsign(float v) {
    return (v > 0.0f) ? 1.0f : ((v < 0.0f) ? -1.0f : 0.0f);
}

// Stage one 128-channel chunk (3200 floats = 800 float4) of w[o] into LDS,
// linear, block-cooperative, fully coalesced (each wave 1KB/instr).
// 3 full rounds (all 4 waves) + tail (first half of wave 0).
__device__ __forceinline__ void stage_chunk(const float* __restrict__ gsrc,
                                            float* lds, int lane, int wv) {
    #pragma unroll
    for (int r = 0; r < 3; ++r) {
        const int e = r * 256 + wv * 64;             // wave-uniform float4 base
        __builtin_amdgcn_global_load_lds((gu32*)(gsrc + 4 * (e + lane)),
                                         (lu32*)(lds + 4 * e), 16, 0, 0);
    }
    if (wv == 0 && lane < 32) {
        __builtin_amdgcn_global_load_lds((gu32*)(gsrc + 4 * (768 + lane)),
                                         (lu32*)(lds + 4 * 768), 16, 0, 0);
    }
}

// G[tap][n][o] = sum_c sign(values[n][c])*sign(w[o][c][tap]) via ballot+popcount.
// One block per o, R3 structure (block-coop staging, syncthreads drains,
// 8 blocks/CU = 32 waves/CU) with the pack pass FUSED into the accumulate:
// wave wv owns taps {wv, wv+4, ...}, lanes 0..9 own n -> unique (tap,n) owner,
// no s_wnz round-trip, no atomics, no separate vpack kernel, 2 barriers/chunk.
__global__ __launch_bounds__(256, 8) void g_kernel(
        const float* __restrict__ values,
        const float* __restrict__ w,
        float* __restrict__ G) {
    const int o    = blockIdx.x;
    const int t    = threadIdx.x;
    const int lane = t & 63;
    const int wv   = t >> 6;

    __shared__ float buf[CHUNK * TAPS];             // 12.8 KB, single buffer
    __shared__ unsigned long long s_vnz[32 * NV];   // [g][n]
    __shared__ unsigned long long s_vng[32 * NV];

    const float* wo = w + (size_t)o * (DD * TAPS);

    // chunk 0 into flight first
    stage_chunk(wo, buf, lane, wv);

    // value sign/nonzero masks (values = 80 KB, L2-hot); overlaps chunk-0 flight
    for (int t2 = wv; t2 < 32 * NV; t2 += 4) {      // t2 wave-uniform
        const int g = t2 / NV;
        const int n = t2 - g * NV;
        float f = values[n * DD + g * 64 + lane];
        unsigned long long nz = __ballot(f != 0.0f);
        unsigned long long ng = __ballot(f < 0.0f);
        if (lane == 0) { s_vnz[g * NV + n] = nz; s_vng[g * NV + n] = ng; }
    }
    __syncthreads();   // drains vmcnt(0): chunk 0 staged; masks visible

    int acc[7] = {0, 0, 0, 0, 0, 0, 0};            // lanes 0..9: (tap = 4k+wv, n = lane)

    for (int ch = 0; ch < NCH; ++ch) {
        // masks for this chunk's two 64-channel groups
        unsigned long long vz0 = 0, vg0 = 0, vz1 = 0, vg1 = 0;
        if (lane < NV) {
            const int g0 = ch * 2;
            vz0 = s_vnz[g0 * NV + lane];       vg0 = s_vng[g0 * NV + lane];
            vz1 = s_vnz[(g0 + 1) * NV + lane]; vg1 = s_vng[(g0 + 1) * NV + lane];
        }
        #pragma unroll
        for (int k = 0; k < 7; ++k) {
            const int tap = 4 * k + wv;
            if (tap < TAPS) {
                // lane = channel-in-group; stride-25 words -> 2 lanes/bank, conflict-free
                float f0 = buf[lane * TAPS + tap];           // channels 0..63
                float f1 = buf[(64 + lane) * TAPS + tap];    // channels 64..127
                unsigned long long wng0 = __ballot(f0 <  0.0f);
                unsigned long long wnz0 = __ballot(f0 != 0.0f);
                unsigned long long wng1 = __ballot(f1 <  0.0f);
                unsigned long long wnz1 = __ballot(f1 != 0.0f);
                // exact: S += popc(bothnz) - 2*popc(signdiff & bothnz); zeros handled
                unsigned long long nzb0 = wnz0 & vz0;
                unsigned long long nzb1 = wnz1 & vz1;
                acc[k] += (int)__popcll(nzb0) - 2 * (int)__popcll((wng0 ^ vg0) & nzb0)
                        + (int)__popcll(nzb1) - 2 * (int)__popcll((wng1 ^ vg1) & nzb1);
            }
        }
        if (ch + 1 < NCH) {
            __syncthreads();                         // all waves done reading buf
            stage_chunk(wo + (size_t)(ch + 1) * (CHUNK * TAPS), buf, lane, wv);
            __syncthreads();                         // vmcnt(0) drain: chunk staged
        }
    }

    // unique ownership -> plain stores, no reduction needed
    if (lane < NV) {
        #pragma unroll
        for (int k = 0; k < 7; ++k) {
            const int tap = 4 * k + wv;
            if (tap < TAPS) {
                G[((size_t)(tap * NV + lane) << 11) + o] = (float)acc[k];
            }
        }
    }
}

// out[b,o,oh,ow] = sign(sum_tap G[idx(tap)][o][tap] + bias[o])
// tap-sum is an exact integer in f32; bias added ONCE at the end (bit-exact sign).
__global__ __launch_bounds__(256) void out_kernel(
        const float* __restrict__ x,
        const float* __restrict__ G,
        const float* __restrict__ bias,
        float* __restrict__ out) {
    const int bb    = blockIdx.x;
    const int half  = bb & 1;
    const int bq    = bb >> 1;
    const int b     = bq >> 5;
    const int oc    = bq & 31;
    const int obase = oc * OB;
    const int t     = threadIdx.x;

    __shared__ int   s_idx[28 * 28];
    __shared__ float s_out[OB * 73];     // [o_l][pos_local], odd stride: conflict-free

    for (int e = t; e < 28 * 28; e += 256) {
        s_idx[e] = (int)(x[b * 784 + e] * 9.0f);   // trunc, matches .astype(int32)
    }
    __syncthreads();

    const int o_l = t & (OB - 1);
    const int pg  = t >> 6;
    const float bv = bias[obase + o_l];
    const float* Gb = G + obase + o_l;

    for (int p0 = 0; p0 < 72; p0 += 4) {
        const int pos = half * 72 + p0 + pg;
        const int oh  = pos / 12;
        const int ow  = pos - oh * 12;
        float acc = 0.0f;                              // integer-exact accumulation
        #pragma unroll
        for (int kh = 0; kh < 5; ++kh) {
            const int row = (oh * 2 + kh) * 28 + ow * 2;
            #pragma unroll
            for (int kw = 0; kw < 5; ++kw) {
                const int nn = s_idx[row + kw];            // wave-uniform broadcast
                const int tp = kh * 5 + kw;
                acc += Gb[(size_t)(tp * NV + nn) << 11];   // coalesced, L2-hit
            }
        }
        s_out[o_l * 73 + p0 + pg] = bsign(acc + bv);
    }
    __syncthreads();

    float* dst = out + ((size_t)(b * DD + obase)) * 144;
    for (int e = t; e < OB * 72; e += 256) {
        const int ol = e / 72;
        const int pp = e - ol * 72;
        dst[ol * 144 + half * 72 + pp] = s_out[ol * 73 + pp];
    }
}

extern "C" void kernel_launch(void* const* d_in, const int* in_sizes, int n_in,
                              void* d_out, int out_size, void* d_ws, size_t ws_size,
                              hipStream_t stream) {
    const float* x      = (const float*)d_in[0];   // [16,1,28,28]
    const float* values = (const float*)d_in[1];   // [10,2048]
    const float* w      = (const float*)d_in[2];   // [2048,2048,5,5] OIHW
    const float* bias   = (const float*)d_in[3];   // [2048]
    float* out = (float*)d_out;                    // [16,2048,12,12]
    float* G   = (float*)d_ws;                     // 25*10*2048 floats = 2 MB scratch

    hipLaunchKernelGGL(g_kernel, dim3(DD), dim3(256), 0, stream, values, w, G);
    hipLaunchKernelGGL(out_kernel, dim3(16 * (DD / OB) * 2), dim3(256), 0, stream, x, G, bias, out);
}

// Round 8
// 157.125 us; speedup vs baseline: 1.0323x; 1.0323x over previous
//
#include <hip/hip_runtime.h>

#define NV    10
#define DD    2048
#define TAPS  25
#define CHUNK 128               // channels per staged chunk
#define NCH   (DD / CHUNK)      // 16 chunks
#define OB    64

typedef __attribute__((address_space(1))) const unsigned int gu32;
typedef __attribute__((address_space(3))) unsigned int lu32;

__device__ __forceinline__ float bsign(float v) {
    return (v > 0.0f) ? 1.0f : ((v < 0.0f) ? -1.0f : 0.0f);
}

// Stage one 128-channel chunk (3200 floats = 800 float4) of w[o] into LDS,
// linear, block-cooperative, fully coalesced (each wave 1KB/instr).
__device__ __forceinline__ void stage_chunk(const float* __restrict__ gsrc,
                                            float* lds, int lane, int wv) {
    #pragma unroll
    for (int r = 0; r < 3; ++r) {
        const int e = r * 256 + wv * 64;             // wave-uniform float4 base
        __builtin_amdgcn_global_load_lds((gu32*)(gsrc + 4 * (e + lane)),
                                         (lu32*)(lds + 4 * e), 16, 0, 0);
    }
    if (wv == 0 && lane < 32) {
        __builtin_amdgcn_global_load_lds((gu32*)(gsrc + 4 * (768 + lane)),
                                         (lu32*)(lds + 4 * 768), 16, 0, 0);
    }
}

// G[tap][n][o] = sum_c sign(values[n][c])*sign(w[o][c][tap]) via ballot+popcount.
// R3's proven shell (block-coop global_load_lds staging, __syncthreads drains,
// LDS-limited 8 blocks/CU) + fused pack/accumulate (wave wv owns taps {wv,wv+4,..},
// lanes 0..9 own n -> unique (tap,n) owner; no s_wnz round-trip, no atomics,
// no vpack kernel, 2 barriers/chunk). NO min-wave pin: let the allocator breathe
// (R7's (256,8) pin caps VGPRs at 64 -> spills in the hot loop; suspected cause
// of its 162 vs R3's 137).
__global__ __launch_bounds__(256) void g_kernel(
        const float* __restrict__ values,
        const float* __restrict__ w,
        float* __restrict__ G) {
    const int o    = blockIdx.x;
    const int t    = threadIdx.x;
    const int lane = t & 63;
    const int wv   = t >> 6;

    __shared__ float buf[CHUNK * TAPS];             // 12.8 KB, single buffer
    __shared__ unsigned long long s_vnz[32 * NV];   // [g][n]
    __shared__ unsigned long long s_vng[32 * NV];

    const float* wo = w + (size_t)o * (DD * TAPS);

    // chunk 0 into flight first
    stage_chunk(wo, buf, lane, wv);

    // value sign/nonzero masks (values = 80 KB, L2-hot); overlaps chunk-0 flight
    for (int t2 = wv; t2 < 32 * NV; t2 += 4) {      // t2 wave-uniform
        const int g = t2 / NV;
        const int n = t2 - g * NV;
        float f = values[n * DD + g * 64 + lane];
        unsigned long long nz = __ballot(f != 0.0f);
        unsigned long long ng = __ballot(f < 0.0f);
        if (lane == 0) { s_vnz[g * NV + n] = nz; s_vng[g * NV + n] = ng; }
    }
    __syncthreads();   // drains vmcnt(0): chunk 0 staged; masks visible

    int acc[7] = {0, 0, 0, 0, 0, 0, 0};            // lanes 0..9: (tap = 4k+wv, n = lane)

    for (int ch = 0; ch < NCH; ++ch) {
        // masks for this chunk's two 64-channel groups
        unsigned long long vz0 = 0, vg0 = 0, vz1 = 0, vg1 = 0;
        if (lane < NV) {
            const int g0 = ch * 2;
            vz0 = s_vnz[g0 * NV + lane];       vg0 = s_vng[g0 * NV + lane];
            vz1 = s_vnz[(g0 + 1) * NV + lane]; vg1 = s_vng[(g0 + 1) * NV + lane];
        }
        #pragma unroll
        for (int k = 0; k < 7; ++k) {
            const int tap = 4 * k + wv;
            if (tap < TAPS) {
                // lane = channel-in-group; stride-25 words -> 2 lanes/bank, conflict-free
                float f0 = buf[lane * TAPS + tap];           // channels 0..63
                float f1 = buf[(64 + lane) * TAPS + tap];    // channels 64..127
                unsigned long long wng0 = __ballot(f0 <  0.0f);
                unsigned long long wnz0 = __ballot(f0 != 0.0f);
                unsigned long long wng1 = __ballot(f1 <  0.0f);
                unsigned long long wnz1 = __ballot(f1 != 0.0f);
                // exact: S += popc(bothnz) - 2*popc(signdiff & bothnz); zeros handled
                unsigned long long nzb0 = wnz0 & vz0;
                unsigned long long nzb1 = wnz1 & vz1;
                acc[k] += (int)__popcll(nzb0) - 2 * (int)__popcll((wng0 ^ vg0) & nzb0)
                        + (int)__popcll(nzb1) - 2 * (int)__popcll((wng1 ^ vg1) & nzb1);
            }
        }
        if (ch + 1 < NCH) {
            __syncthreads();                         // all waves done reading buf
            stage_chunk(wo + (size_t)(ch + 1) * (CHUNK * TAPS), buf, lane, wv);
            __syncthreads();                         // vmcnt(0) drain: chunk staged
        }
    }

    // unique ownership -> plain stores, no reduction needed
    if (lane < NV) {
        #pragma unroll
        for (int k = 0; k < 7; ++k) {
            const int tap = 4 * k + wv;
            if (tap < TAPS) {
                G[((size_t)(tap * NV + lane) << 11) + o] = (float)acc[k];
            }
        }
    }
}

// out[b,o,oh,ow] = sign(sum_tap G[idx(tap)][o][tap] + bias[o])
// R3's verbatim 512-block version (part of the 137.3 best measurement).
// tap-sum is an exact integer in f32; bias added ONCE at the end (bit-exact sign).
__global__ __launch_bounds__(256) void out_kernel(
        const float* __restrict__ x,
        const float* __restrict__ G,
        const float* __restrict__ bias,
        float* __restrict__ out) {
    const int b     = blockIdx.x >> 5;
    const int oc    = blockIdx.x & 31;
    const int obase = oc * OB;
    const int t     = threadIdx.x;

    __shared__ int   s_idx[28 * 28];
    __shared__ float s_out[OB * 145];    // [o_l][pos], odd word-stride: conflict-free

    for (int e = t; e < 28 * 28; e += 256) {
        s_idx[e] = (int)(x[b * 784 + e] * 9.0f);   // trunc, matches .astype(int32)
    }
    __syncthreads();

    const int o_l = t & (OB - 1);
    const int pg  = t >> 6;
    const float bv = bias[obase + o_l];
    const float* Gb = G + obase + o_l;

    for (int p0 = 0; p0 < 144; p0 += 4) {
        const int pos = p0 + pg;
        const int oh  = pos / 12;
        const int ow  = pos - oh * 12;
        float acc = 0.0f;                              // integer-exact accumulation
        #pragma unroll
        for (int kh = 0; kh < 5; ++kh) {
            const int row = (oh * 2 + kh) * 28 + ow * 2;
            #pragma unroll
            for (int kw = 0; kw < 5; ++kw) {
                const int nn = s_idx[row + kw];            // wave-uniform broadcast
                const int tp = kh * 5 + kw;
                acc += Gb[(size_t)(tp * NV + nn) << 11];   // coalesced 256B/wave, L2-hit
            }
        }
        s_out[o_l * 145 + pos] = bsign(acc + bv);
    }
    __syncthreads();

    // block's output region is one contiguous span of OB*144 floats
    float* dst = out + ((size_t)(b * DD + obase)) * 144;
    for (int e = t; e < OB * 144; e += 256) {
        const int ol = e / 144;
        dst[e] = s_out[ol * 145 + (e - ol * 144)];
    }
}

extern "C" void kernel_launch(void* const* d_in, const int* in_sizes, int n_in,
                              void* d_out, int out_size, void* d_ws, size_t ws_size,
                              hipStream_t stream) {
    const float* x      = (const float*)d_in[0];   // [16,1,28,28]
    const float* values = (const float*)d_in[1];   // [10,2048]
    const float* w      = (const float*)d_in[2];   // [2048,2048,5,5] OIHW
    const float* bias   = (const float*)d_in[3];   // [2048]
    float* out = (float*)d_out;                    // [16,2048,12,12]
    float* G   = (float*)d_ws;                     // 25*10*2048 floats = 2 MB scratch

    hipLaunchKernelGGL(g_kernel, dim3(DD), dim3(256), 0, stream, values, w, G);
    hipLaunchKernelGGL(out_kernel, dim3(16 * (DD / OB)), dim3(256), 0, stream, x, G, bias, out);
}

// Round 9
// 156.321 us; speedup vs baseline: 1.0376x; 1.0051x over previous
//
#include <hip/hip_runtime.h>

#define NV    10
#define DD    2048
#define TAPS  25
#define CHUNK 128               // channels per staged chunk
#define NCH   (DD / CHUNK)      // 16 chunks
#define OB    64

__device__ __forceinline__ float bsign(float v) {
    return (v > 0.0f) ? 1.0f : ((v < 0.0f) ? -1.0f : 0.0f);
}

// G[tap][n][o] = sum_c sign(values[n][c])*sign(w[o][c][tap]) via ballot+popcount.
// R9: reg-staged T14 pipeline. Thread t owns float4 slots {t, t+256, t+512} (+t<32: 768+t)
// of each 800-float4 chunk. Loads go to REGISTERS (m13-proven per-lane float4 path),
// ds_write to LDS happens after the compute barrier; next chunk's loads issue right
// after. Raw s_barrier + lgkmcnt(0) only -- vmcnt NEVER drained at a barrier, so
// global loads stay in flight during every compute phase (no convoy duty-cycle loss).
__global__ __launch_bounds__(256) void g_kernel(
        const float* __restrict__ values,
        const float* __restrict__ w,
        float* __restrict__ G) {
    const int o    = blockIdx.x;
    const int t    = threadIdx.x;
    const int lane = t & 63;
    const int wv   = t >> 6;

    __shared__ float4 buf4[CHUNK * TAPS / 4];       // 800 float4 = 12.8 KB, single buffer
    __shared__ unsigned long long s_vnz[32 * NV];   // [g][n]
    __shared__ unsigned long long s_vng[32 * NV];

    const float4* wf4 = (const float4*)(w + (size_t)o * (DD * TAPS));  // 800 f4 per chunk

    // value sign/nonzero masks (values = 80 KB, L2/L3-hot); issued before reg-loads
    for (int t2 = wv; t2 < 32 * NV; t2 += 4) {      // t2 wave-uniform
        const int g = t2 / NV;
        const int n = t2 - g * NV;
        float f = values[n * DD + g * 64 + lane];
        unsigned long long nz = __ballot(f != 0.0f);
        unsigned long long ng = __ballot(f < 0.0f);
        if (lane == 0) { s_vnz[g * NV + n] = nz; s_vng[g * NV + n] = ng; }
    }

    float4 r0, r1, r2, r3;
    #define LOADREGS(ch) do {                                   \
        const float4* p_ = wf4 + (size_t)(ch) * 800;            \
        r0 = p_[t]; r1 = p_[t + 256]; r2 = p_[t + 512];         \
        if (t < 32) r3 = p_[t + 768];                           \
    } while (0)
    #define WRITEREGS() do {                                    \
        buf4[t] = r0; buf4[t + 256] = r1; buf4[t + 512] = r2;   \
        if (t < 32) buf4[t + 768] = r3;                         \
    } while (0)

    LOADREGS(0);
    WRITEREGS();                                     // waits vmcnt via r* data deps only
    LOADREGS(1);                                     // chunk 1 into flight
    asm volatile("s_waitcnt lgkmcnt(0)" ::: "memory");
    __builtin_amdgcn_s_barrier();                    // buf = chunk 0; masks visible

    int acc[7] = {0, 0, 0, 0, 0, 0, 0};             // lanes 0..9: (tap = 4k+wv, n = lane)
    const float* buf = (const float*)buf4;

    for (int ch = 0; ch < NCH; ++ch) {
        unsigned long long vz0 = 0, vg0 = 0, vz1 = 0, vg1 = 0;
        if (lane < NV) {
            const int g0 = ch * 2;
            vz0 = s_vnz[g0 * NV + lane];       vg0 = s_vng[g0 * NV + lane];
            vz1 = s_vnz[(g0 + 1) * NV + lane]; vg1 = s_vng[(g0 + 1) * NV + lane];
        }
        #pragma unroll
        for (int k = 0; k < 7; ++k) {
            const int tap = 4 * k + wv;              // wave wv owns taps {wv, wv+4, ...}
            if (tap < TAPS) {
                // lane = channel-in-group; stride-25 words -> 2 lanes/bank, conflict-free
                float f0 = buf[lane * TAPS + tap];           // channels 0..63
                float f1 = buf[(64 + lane) * TAPS + tap];    // channels 64..127
                unsigned long long wng0 = __ballot(f0 <  0.0f);
                unsigned long long wnz0 = __ballot(f0 != 0.0f);
                unsigned long long wng1 = __ballot(f1 <  0.0f);
                unsigned long long wnz1 = __ballot(f1 != 0.0f);
                // exact: S += popc(bothnz) - 2*popc(signdiff & bothnz); zeros handled
                unsigned long long nzb0 = wnz0 & vz0;
                unsigned long long nzb1 = wnz1 & vz1;
                acc[k] += (int)__popcll(nzb0) - 2 * (int)__popcll((wng0 ^ vg0) & nzb0)
                        + (int)__popcll(nzb1) - 2 * (int)__popcll((wng1 ^ vg1) & nzb1);
            }
        }
        __builtin_amdgcn_s_barrier();                // all waves done reading buf (ds_read
                                                     // results consumed pre-arrival; no vmcnt drain)
        if (ch + 1 < NCH) {
            WRITEREGS();                             // regs hold ch+1 (landed during compute)
            if (ch + 2 < NCH) LOADREGS(ch + 2);      // next loads into flight immediately
            asm volatile("s_waitcnt lgkmcnt(0)" ::: "memory");
            __builtin_amdgcn_s_barrier();            // buf = ch+1 ready; vmcnt still in flight
        }
    }
    #undef LOADREGS
    #undef WRITEREGS

    // unique (tap,n) ownership -> plain stores, no reduction needed
    if (lane < NV) {
        #pragma unroll
        for (int k = 0; k < 7; ++k) {
            const int tap = 4 * k + wv;
            if (tap < TAPS) {
                G[((size_t)(tap * NV + lane) << 11) + o] = (float)acc[k];
            }
        }
    }
}

// out[b,o,oh,ow] = sign(sum_tap G[idx(tap)][o][tap] + bias[o])  -- unchanged from R8.
// tap-sum is an exact integer in f32; bias added ONCE at the end (bit-exact sign).
__global__ __launch_bounds__(256) void out_kernel(
        const float* __restrict__ x,
        const float* __restrict__ G,
        const float* __restrict__ bias,
        float* __restrict__ out) {
    const int b     = blockIdx.x >> 5;
    const int oc    = blockIdx.x & 31;
    const int obase = oc * OB;
    const int t     = threadIdx.x;

    __shared__ int   s_idx[28 * 28];
    __shared__ float s_out[OB * 145];    // [o_l][pos], odd word-stride: conflict-free

    for (int e = t; e < 28 * 28; e += 256) {
        s_idx[e] = (int)(x[b * 784 + e] * 9.0f);   // trunc, matches .astype(int32)
    }
    __syncthreads();

    const int o_l = t & (OB - 1);
    const int pg  = t >> 6;
    const float bv = bias[obase + o_l];
    const float* Gb = G + obase + o_l;

    for (int p0 = 0; p0 < 144; p0 += 4) {
        const int pos = p0 + pg;
        const int oh  = pos / 12;
        const int ow  = pos - oh * 12;
        float acc = 0.0f;                              // integer-exact accumulation
        #pragma unroll
        for (int kh = 0; kh < 5; ++kh) {
            const int row = (oh * 2 + kh) * 28 + ow * 2;
            #pragma unroll
            for (int kw = 0; kw < 5; ++kw) {
                const int nn = s_idx[row + kw];            // wave-uniform broadcast
                const int tp = kh * 5 + kw;
                acc += Gb[(size_t)(tp * NV + nn) << 11];   // coalesced 256B/wave, L2-hit
            }
        }
        s_out[o_l * 145 + pos] = bsign(acc + bv);
    }
    __syncthreads();

    // block's output region is one contiguous span of OB*144 floats
    float* dst = out + ((size_t)(b * DD + obase)) * 144;
    for (int e = t; e < OB * 144; e += 256) {
        const int ol = e / 144;
        dst[e] = s_out[ol * 145 + (e - ol * 144)];
    }
}

extern "C" void kernel_launch(void* const* d_in, const int* in_sizes, int n_in,
                              void* d_out, int out_size, void* d_ws, size_t ws_size,
                              hipStream_t stream) {
    const float* x      = (const float*)d_in[0];   // [16,1,28,28]
    const float* values = (const float*)d_in[1];   // [10,2048]
    const float* w      = (const float*)d_in[2];   // [2048,2048,5,5] OIHW
    const float* bias   = (const float*)d_in[3];   // [2048]
    float* out = (float*)d_out;                    // [16,2048,12,12]
    float* G   = (float*)d_ws;                     // 25*10*2048 floats = 2 MB scratch

    hipLaunchKernelGGL(g_kernel, dim3(DD), dim3(256), 0, stream, values, w, G);
    hipLaunchKernelGGL(out_kernel, dim3(16 * (DD / OB)), dim3(256), 0, stream, x, G, bias, out);
}